// Round 25
// baseline (34.062 us; speedup 1.0000x reference)
//
#include <hip/hip_runtime.h>
#include <hip/hip_fp16.h>
#include <math.h>
#include <stdint.h>

#define B 8
#define L 256
#define DM 512
#define NH 16
#define APO 128
#define VOC 128
#define EMB (L * B * DM)   // 1048576 floats

typedef __attribute__((ext_vector_type(8))) _Float16 half8v;  // 4 VGPR
typedef __attribute__((ext_vector_type(4))) float float4v;    // MFMA C/D

// ws layout:
//   byte 1024..9215  : wsB ushort[4096] = lw' f16 B-frags (16x16x32 layout)
//   byte 9216..17407 : order int[2048] = flat (bi*256+i) counting-sorted by a_i
//   byte 24576..+4MB : fp8 packed table [a_i][a_j][256B], unit U at U^(a_j&15)
//                      w' = w*beta/sigma_k ; b' = (b-mean_k)*beta/sigma_k (e4m3)
#define WSB_BOFF   1024
#define ORD_BOFF   9216
#define PACK_BOFF  24576
#define PACK_BYTES (128 * 128 * 256)
#define WS_NEED    ((size_t)PACK_BOFF + (size_t)PACK_BYTES)

__device__ __forceinline__ void g2lds16(const void* g, void* l) {
    __builtin_amdgcn_global_load_lds(
        (const __attribute__((address_space(1))) unsigned int*)g,
        (__attribute__((address_space(3))) unsigned int*)l, 16, 0, 0);
}

// ========== pack (+prep & a_i-sort on block 0) ================================
__global__ __launch_bounds__(256) void pack_kernel(const float* __restrict__ wtab,
                                                   const float* __restrict__ btab,
                                                   const float* __restrict__ means,
                                                   const float* __restrict__ stds,
                                                   const float* __restrict__ lin_w,
                                                   const int* __restrict__ atoms,
                                                   float* __restrict__ ws) {
    const float beta = sqrtf(0.5f * 1.4426950408889634f);  // exp(-.5x^2)=exp2(-(x*beta)^2)
    const float gscale = 0.3989422804014327f;              // 1/sqrt(2*pi)
    int t = threadIdx.x;

    if (blockIdx.x == 0) {
        unsigned short* wsB = (unsigned short*)((char*)ws + WSB_BOFF);
        for (int idx = t; idx < 4 * 64 * 8; idx += 256) {
            int p = idx >> 9;
            int lane = (idx >> 3) & 63;
            int e = idx & 7;
            int k = p * 32 + ((lane >> 4) << 3) + e;
            int h = lane & 15;
            float sigma = fabsf(stds[k]) + 1e-5f;
            float v = lin_w[k * NH + h] * (gscale / sigma);
            __half hv = __float2half(v);
            wsB[idx] = *reinterpret_cast<unsigned short*>(&hv);
        }
        __shared__ int hist[128];
        if (t < 128) hist[t] = 0;
        __syncthreads();
        for (int vb = t; vb < 2048; vb += 256)
            atomicAdd(&hist[atoms[vb] & 127], 1);
        __syncthreads();
        __shared__ int offs[128];
        if (t == 0) {
            int acc = 0;
            for (int bkt = 0; bkt < 128; ++bkt) { offs[bkt] = acc; acc += hist[bkt]; }
        }
        __syncthreads();
        int* order = (int*)((char*)ws + ORD_BOFF);
        for (int vb = t; vb < 2048; vb += 256) {
            int a = atoms[vb] & 127;
            int pos = atomicAdd(&offs[a], 1);
            order[pos] = vb;
        }
    }

    int idx = blockIdx.x * 256 + t;  // 0..262143: one 16B unit
    int r = idx >> 4;                // a_i*128 + a_j
    int a_i = r >> 7, a_j = r & 127;
    int U = idx & 15;
    int k0 = U * 8;
    size_t src = ((size_t)a_j * VOC + a_i) * APO + k0;
    const float4* w4p = (const float4*)(wtab + src);
    const float4* b4p = (const float4*)(btab + src);
    float4 w0 = w4p[0], w1 = w4p[1], b0 = b4p[0], b1 = b4p[1];
    float wq[8], bq[8];
    #pragma unroll
    for (int e = 0; e < 8; ++e) {
        int k = k0 + e;
        float sigma = fabsf(stds[k]) + 1e-5f;
        float ia = beta / sigma;
        float wvv = ((e < 4) ? ((const float*)&w0)[e] : ((const float*)&w1)[e - 4]) * ia;
        float bvv = (((e < 4) ? ((const float*)&b0)[e] : ((const float*)&b1)[e - 4])
                     - means[k]) * ia;
        wq[e] = wvv; bq[e] = bvv;
    }
    int wlo = 0, whi = 0, blo = 0, bhi = 0;
    wlo = __builtin_amdgcn_cvt_pk_fp8_f32(wq[0], wq[1], wlo, 0);
    wlo = __builtin_amdgcn_cvt_pk_fp8_f32(wq[2], wq[3], wlo, 1);
    whi = __builtin_amdgcn_cvt_pk_fp8_f32(wq[4], wq[5], whi, 0);
    whi = __builtin_amdgcn_cvt_pk_fp8_f32(wq[6], wq[7], whi, 1);
    blo = __builtin_amdgcn_cvt_pk_fp8_f32(bq[0], bq[1], blo, 0);
    blo = __builtin_amdgcn_cvt_pk_fp8_f32(bq[2], bq[3], blo, 1);
    bhi = __builtin_amdgcn_cvt_pk_fp8_f32(bq[4], bq[5], bhi, 0);
    bhi = __builtin_amdgcn_cvt_pk_fp8_f32(bq[6], bq[7], bhi, 1);
    int pu = U ^ (a_j & 15);
    uint4 o;
    o.x = (unsigned)wlo; o.y = (unsigned)whi;
    o.z = (unsigned)blo; o.w = (unsigned)bhi;
    *(uint4*)((char*)ws + PACK_BOFF + (size_t)r * 256 + (size_t)pu * 16) = o;
}

// ================= fused pair kernel: 2 sorted slots per block =================
// Stage slice(vb0) once; if a_i matches (common: ~16 dup/bin after sort) vb1
// reuses it FREE; else restage once. Both epilogues after both computes reuse
// the dead stage as cbuf. Grid = 1024 = exactly 4 blocks/CU, all co-resident.
__global__ __launch_bounds__(256, 4) void pair_fused(const int* __restrict__ atoms,
                                                     const int* __restrict__ chirals,
                                                     const float* __restrict__ coords,
                                                     const int* __restrict__ bonds,
                                                     const float* __restrict__ atype,
                                                     const float* __restrict__ chiral,
                                                     const float* __restrict__ bond_emb,
                                                     const float* __restrict__ lin_b,
                                                     const float* __restrict__ ws,
                                                     float* __restrict__ out) {
    __shared__ __align__(16) char stage[32 * 1024];

    int t = threadIdx.x;
    int p = blockIdx.x;              // 0..1023
    const int* order = (const int*)((const char*)ws + ORD_BOFF);
    int slot = (p & 7) * 256 + (p >> 3) * 2;    // XCD-chunked, bijective
    int vb0 = order[slot], vb1 = order[slot + 1];
    int bi0 = vb0 >> 8, i0 = vb0 & 255;
    int bi1 = vb1 >> 8, i1 = vb1 & 255;
    int w = t >> 6, l = t & 63;
    int m = l >> 4;

    int a_i0 = atoms[vb0];           // flat idx == bi*L+i
    int a_i1 = atoms[vb1];
    int av0 = atoms[bi0 * L + t];
    int av1 = atoms[bi1 * L + t];

    // ---- stage slice 0 immediately (prologue overlaps the burst)
    const char* pk0 = (const char*)ws + PACK_BOFF + (size_t)a_i0 * 32768;
    #pragma unroll
    for (int it = 0; it < 8; ++it) {
        size_t off = (size_t)(w * 32 + it * 4) * 256 + (size_t)l * 16;
        g2lds16(pk0 + off, stage + off);
    }

    // ---- distances for both outputs
    float d0, d1;
    {
        float cix = coords[((size_t)bi0 * L + i0) * 3 + 0];
        float ciy = coords[((size_t)bi0 * L + i0) * 3 + 1];
        float ciz = coords[((size_t)bi0 * L + i0) * 3 + 2];
        float cjx = coords[((size_t)bi0 * L + t) * 3 + 0];
        float cjy = coords[((size_t)bi0 * L + t) * 3 + 1];
        float cjz = coords[((size_t)bi0 * L + t) * 3 + 2];
        float dx = cjx - cix, dy = cjy - ciy, dz = cjz - ciz;
        float s2 = dx * dx + dy * dy + dz * dz;
        d0 = (s2 > 0.0f) ? sqrtf(s2) : 0.0f;
        cix = coords[((size_t)bi1 * L + i1) * 3 + 0];
        ciy = coords[((size_t)bi1 * L + i1) * 3 + 1];
        ciz = coords[((size_t)bi1 * L + i1) * 3 + 2];
        cjx = coords[((size_t)bi1 * L + t) * 3 + 0];
        cjy = coords[((size_t)bi1 * L + t) * 3 + 1];
        cjz = coords[((size_t)bi1 * L + t) * 3 + 2];
        dx = cjx - cix; dy = cjy - ciy; dz = cjz - ciz;
        s2 = dx * dx + dy * dy + dz * dz;
        d1 = (s2 > 0.0f) ? sqrtf(s2) : 0.0f;
    }

    // B-frags preload (4 passes x 8 f16)
    half8v bfrag[4];
    {
        const uint4* wb = (const uint4*)((const char*)ws + WSB_BOFF);
        #pragma unroll
        for (int pp = 0; pp < 4; ++pp) {
            uint4 r = wb[pp * 64 + l];
            bfrag[pp] = *reinterpret_cast<half8v*>(&r);
        }
    }

    // descriptors for both outputs
    float dval0[4], dval1[4];
    int base0[4], ax0[4], base1[4], ax1[4];
    {
        int db0 = __float_as_int(d0), db1 = __float_as_int(d1);
        #pragma unroll
        for (int q = 0; q < 4; ++q) {
            int idx4 = (q * 16 + (l & 15)) * 4;
            int a0 = __builtin_amdgcn_ds_bpermute(idx4, av0);
            int a1 = __builtin_amdgcn_ds_bpermute(idx4, av1);
            dval0[q] = __int_as_float(__builtin_amdgcn_ds_bpermute(idx4, db0));
            dval1[q] = __int_as_float(__builtin_amdgcn_ds_bpermute(idx4, db1));
            base0[q] = a0 * 256; ax0[q] = a0 & 15;
            base1[q] = a1 * 256; ax1[q] = a1 & 15;
        }
    }

    float4v acc0[4], acc1[4];
    #pragma unroll
    for (int q = 0; q < 4; ++q) {
        float4v z = {0, 0, 0, 0};
        acc0[q] = z; acc1[q] = z;
    }

#define COMPUTE(ACC, DVAL, BASE, AX)                                            \
    {                                                                           \
        _Pragma("unroll")                                                       \
        for (int rr = 0; rr < 4; ++rr) {                                        \
            _Pragma("unroll")                                                   \
            for (int q = 0; q < 4; ++q) {                                       \
                int un = (rr * 4 + m) ^ AX[q];                                  \
                uint4 u = *(const uint4*)(stage + BASE[q] + (un << 4));         \
                auto w01 = __builtin_amdgcn_cvt_pk_f32_fp8((int)u.x, 0);        \
                auto w23 = __builtin_amdgcn_cvt_pk_f32_fp8((int)u.x, 1);        \
                auto w45 = __builtin_amdgcn_cvt_pk_f32_fp8((int)u.y, 0);        \
                auto w67 = __builtin_amdgcn_cvt_pk_f32_fp8((int)u.y, 1);        \
                auto b01 = __builtin_amdgcn_cvt_pk_f32_fp8((int)u.z, 0);        \
                auto b23 = __builtin_amdgcn_cvt_pk_f32_fp8((int)u.z, 1);        \
                auto b45 = __builtin_amdgcn_cvt_pk_f32_fp8((int)u.w, 0);        \
                auto b67 = __builtin_amdgcn_cvt_pk_f32_fp8((int)u.w, 1);        \
                float dq = DVAL[q];                                             \
                float t0 = fmaf(w01[0], dq, b01[0]);                            \
                float t1 = fmaf(w01[1], dq, b01[1]);                            \
                float t2 = fmaf(w23[0], dq, b23[0]);                            \
                float t3 = fmaf(w23[1], dq, b23[1]);                            \
                float t4 = fmaf(w45[0], dq, b45[0]);                            \
                float t5 = fmaf(w45[1], dq, b45[1]);                            \
                float t6 = fmaf(w67[0], dq, b67[0]);                            \
                float t7 = fmaf(w67[1], dq, b67[1]);                            \
                float g0 = __builtin_amdgcn_exp2f(-(t0 * t0));                  \
                float g1 = __builtin_amdgcn_exp2f(-(t1 * t1));                  \
                float g2 = __builtin_amdgcn_exp2f(-(t2 * t2));                  \
                float g3 = __builtin_amdgcn_exp2f(-(t3 * t3));                  \
                float g4 = __builtin_amdgcn_exp2f(-(t4 * t4));                  \
                float g5 = __builtin_amdgcn_exp2f(-(t5 * t5));                  \
                float g6 = __builtin_amdgcn_exp2f(-(t6 * t6));                  \
                float g7 = __builtin_amdgcn_exp2f(-(t7 * t7));                  \
                auto p0 = __builtin_amdgcn_cvt_pkrtz(g0, g1);                   \
                auto p1 = __builtin_amdgcn_cvt_pkrtz(g2, g3);                   \
                auto p2 = __builtin_amdgcn_cvt_pkrtz(g4, g5);                   \
                auto p3 = __builtin_amdgcn_cvt_pkrtz(g6, g7);                   \
                uint4 au;                                                       \
                au.x = *reinterpret_cast<unsigned*>(&p0);                       \
                au.y = *reinterpret_cast<unsigned*>(&p1);                       \
                au.z = *reinterpret_cast<unsigned*>(&p2);                       \
                au.w = *reinterpret_cast<unsigned*>(&p3);                       \
                half8v af = *reinterpret_cast<half8v*>(&au);                    \
                ACC[q] = __builtin_amdgcn_mfma_f32_16x16x32_f16(af, bfrag[rr],  \
                                                                ACC[q], 0, 0, 0);\
            }                                                                   \
        }                                                                       \
    }

#define EPILOGUE(ACC, BI, I)                                                    \
    {                                                                           \
        int a_j = atoms[(BI) * L + t];                                          \
        int bvd = bonds[(((size_t)(BI) * L) + (I)) * L + t];                    \
        float beh[NH];                                                          \
        const float4* ber = (const float4*)(bond_emb + (size_t)bvd * NH);       \
        _Pragma("unroll")                                                       \
        for (int u = 0; u < 4; ++u) {                                           \
            float4 v4 = ber[u];                                                 \
            beh[u * 4 + 0] = v4.x; beh[u * 4 + 1] = v4.y;                       \
            beh[u * 4 + 2] = v4.z; beh[u * 4 + 3] = v4.w;                       \
        }                                                                       \
        float* cbuf = (float*)(stage + (size_t)w * 4352);                       \
        {                                                                       \
            int h = l & 15, jg = l >> 4;                                        \
            _Pragma("unroll")                                                   \
            for (int q = 0; q < 4; ++q)                                         \
                *(float4v*)(cbuf + h * 68 + q * 16 + jg * 4) = ACC[q];          \
        }                                                                       \
        asm volatile("s_waitcnt lgkmcnt(0)" ::: "memory");                      \
        __builtin_amdgcn_sched_barrier(0);                                      \
        size_t obase = (((size_t)(BI) * NH) * L + (I)) * L + t;                 \
        float ninf = __uint_as_float(0xff7f0000u);                              \
        bool pad = (a_j == 0);                                                  \
        _Pragma("unroll")                                                       \
        for (int h = 0; h < NH; ++h) {                                          \
            float v = cbuf[h * 68 + l] + lin_b[h] + beh[h];                     \
            out[(size_t)EMB + obase + (size_t)h * L * L] = pad ? ninf : v;      \
        }                                                                       \
    }

    asm volatile("s_waitcnt vmcnt(0)" ::: "memory");
    __syncthreads();                 // slice 0 resident

    // ---- fused emb for both outputs (overlaps compute)
    if (t < 128) {
        int a = atoms[vb0], c = chirals[vb0];
        const float4* va = (const float4*)(atype + (size_t)a * DM);
        const float4* vc = (const float4*)(chiral + (size_t)c * DM);
        float4 x = va[t], y = vc[t];
        x.x += y.x; x.y += y.y; x.z += y.z; x.w += y.w;
        ((float4*)(out + ((size_t)i0 * B + bi0) * DM))[t] = x;
        a = atoms[vb1]; c = chirals[vb1];
        va = (const float4*)(atype + (size_t)a * DM);
        vc = (const float4*)(chiral + (size_t)c * DM);
        float4 x1 = va[t], y1 = vc[t];
        x1.x += y1.x; x1.y += y1.y; x1.z += y1.z; x1.w += y1.w;
        ((float4*)(out + ((size_t)i1 * B + bi1) * DM))[t] = x1;
    }

    COMPUTE(acc0, dval0, base0, ax0)

    if (a_i1 != a_i0) {              // block-uniform branch: restage for vb1
        asm volatile("s_waitcnt lgkmcnt(0)" ::: "memory");
        __syncthreads();             // all reads of slice 0 done
        const char* pk1 = (const char*)ws + PACK_BOFF + (size_t)a_i1 * 32768;
        #pragma unroll
        for (int it = 0; it < 8; ++it) {
            size_t off = (size_t)(w * 32 + it * 4) * 256 + (size_t)l * 16;
            g2lds16(pk1 + off, stage + off);
        }
        asm volatile("s_waitcnt vmcnt(0)" ::: "memory");
        __syncthreads();
    }

    COMPUTE(acc1, dval1, base1, ax1)

    asm volatile("s_waitcnt lgkmcnt(0)" ::: "memory");
    __syncthreads();                 // stage dead -> reuse as cbuf

    EPILOGUE(acc0, bi0, i0)
    EPILOGUE(acc1, bi1, i1)
#undef COMPUTE
#undef EPILOGUE
}

extern "C" void kernel_launch(void* const* d_in, const int* in_sizes, int n_in,
                              void* d_out, int out_size, void* d_ws, size_t ws_size,
                              hipStream_t stream) {
    const int*   atoms    = (const int*)d_in[0];
    const int*   chirals  = (const int*)d_in[1];
    const float* coords   = (const float*)d_in[2];
    const int*   bonds    = (const int*)d_in[3];
    const float* atype    = (const float*)d_in[4];
    const float* chiral   = (const float*)d_in[5];
    const float* wtab     = (const float*)d_in[6];
    const float* btab     = (const float*)d_in[7];
    const float* means    = (const float*)d_in[8];
    const float* stds     = (const float*)d_in[9];
    const float* bond_emb = (const float*)d_in[10];
    const float* lin_w    = (const float*)d_in[11];
    const float* lin_b    = (const float*)d_in[12];
    float* out = (float*)d_out;
    float* ws  = (float*)d_ws;

    pack_kernel<<<1024, 256, 0, stream>>>(wtab, btab, means, stds, lin_w, atoms, ws);
    pair_fused<<<1024, 256, 0, stream>>>(atoms, chirals, coords, bonds,
                                         atype, chiral, bond_emb, lin_b, ws, out);
}

// Round 26
// 32.696 us; speedup vs baseline: 1.0418x; 1.0418x over previous
//
#include <hip/hip_runtime.h>
#include <hip/hip_fp16.h>
#include <math.h>
#include <stdint.h>

#define B 8
#define L 256
#define DM 512
#define NH 16
#define APO 128
#define VOC 128
#define EMB (L * B * DM)   // 1048576 floats

typedef __attribute__((ext_vector_type(8))) _Float16 half8v;  // 4 VGPR
typedef __attribute__((ext_vector_type(4))) float float4v;    // MFMA C/D

// ws layout:
//   byte 1024..9215  : wsB ushort[4096] = lw' f16 B-frags (16x16x32 layout)
//   byte 9216..25599 : order2 int2[2048] = {vb, a_i} counting-sorted by a_i
//   byte 32768..+4MB : fp8 packed table [a_i][a_j][256B], unit U at U^(a_j&15)
//                      w' = w*beta/sigma_k ; b' = (b-mean_k)*beta/sigma_k (e4m3)
#define WSB_BOFF   1024
#define ORD_BOFF   9216
#define PACK_BOFF  32768
#define PACK_BYTES (128 * 128 * 256)
#define WS_NEED    ((size_t)PACK_BOFF + (size_t)PACK_BYTES)

__device__ __forceinline__ void g2lds16(const void* g, void* l) {
    __builtin_amdgcn_global_load_lds(
        (const __attribute__((address_space(1))) unsigned int*)g,
        (__attribute__((address_space(3))) unsigned int*)l, 16, 0, 0);
}

// ========== pack (+prep & a_i-sort on block 0): f32 -> fp8, swizzle baked =====
__global__ __launch_bounds__(256) void pack_kernel(const float* __restrict__ wtab,
                                                   const float* __restrict__ btab,
                                                   const float* __restrict__ means,
                                                   const float* __restrict__ stds,
                                                   const float* __restrict__ lin_w,
                                                   const int* __restrict__ atoms,
                                                   float* __restrict__ ws) {
    const float beta = sqrtf(0.5f * 1.4426950408889634f);  // exp(-.5x^2)=exp2(-(x*beta)^2)
    const float gscale = 0.3989422804014327f;              // 1/sqrt(2*pi)
    int t = threadIdx.x;

    // ---- block-0 side-jobs: lw' B-frags + a_i counting sort (order2 = {vb,a_i})
    if (blockIdx.x == 0) {
        unsigned short* wsB = (unsigned short*)((char*)ws + WSB_BOFF);
        for (int idx = t; idx < 4 * 64 * 8; idx += 256) {
            int p = idx >> 9;
            int lane = (idx >> 3) & 63;
            int e = idx & 7;
            int k = p * 32 + ((lane >> 4) << 3) + e;
            int h = lane & 15;
            float sigma = fabsf(stds[k]) + 1e-5f;
            float v = lin_w[k * NH + h] * (gscale / sigma);
            __half hv = __float2half(v);
            wsB[idx] = *reinterpret_cast<unsigned short*>(&hv);
        }
        __shared__ int hist[128];
        if (t < 128) hist[t] = 0;
        __syncthreads();
        for (int vb = t; vb < 2048; vb += 256)
            atomicAdd(&hist[atoms[vb] & 127], 1);
        __syncthreads();
        __shared__ int offs[128];
        if (t == 0) {
            int acc = 0;
            for (int bkt = 0; bkt < 128; ++bkt) { offs[bkt] = acc; acc += hist[bkt]; }
        }
        __syncthreads();
        int2* order2 = (int2*)((char*)ws + ORD_BOFF);
        for (int vb = t; vb < 2048; vb += 256) {
            int a = atoms[vb] & 127;
            int pos = atomicAdd(&offs[a], 1);
            int2 e; e.x = vb; e.y = a;
            order2[pos] = e;
        }
    }

    // ---- pack: one 16B unit (8 k of w' + 8 k of b') per thread
    int idx = blockIdx.x * 256 + t;  // 0..262143
    int r = idx >> 4;                // packed row: a_i*128 + a_j
    int a_i = r >> 7, a_j = r & 127;
    int U = idx & 15;
    int k0 = U * 8;
    size_t src = ((size_t)a_j * VOC + a_i) * APO + k0;
    const float4* w4p = (const float4*)(wtab + src);
    const float4* b4p = (const float4*)(btab + src);
    float4 w0 = w4p[0], w1 = w4p[1], b0 = b4p[0], b1 = b4p[1];
    float wq[8], bq[8];
    #pragma unroll
    for (int e = 0; e < 8; ++e) {
        int k = k0 + e;
        float sigma = fabsf(stds[k]) + 1e-5f;
        float ia = beta / sigma;
        float wvv = ((e < 4) ? ((const float*)&w0)[e] : ((const float*)&w1)[e - 4]) * ia;
        float bvv = (((e < 4) ? ((const float*)&b0)[e] : ((const float*)&b1)[e - 4])
                     - means[k]) * ia;
        wq[e] = wvv; bq[e] = bvv;
    }
    int wlo = 0, whi = 0, blo = 0, bhi = 0;
    wlo = __builtin_amdgcn_cvt_pk_fp8_f32(wq[0], wq[1], wlo, 0);
    wlo = __builtin_amdgcn_cvt_pk_fp8_f32(wq[2], wq[3], wlo, 1);
    whi = __builtin_amdgcn_cvt_pk_fp8_f32(wq[4], wq[5], whi, 0);
    whi = __builtin_amdgcn_cvt_pk_fp8_f32(wq[6], wq[7], whi, 1);
    blo = __builtin_amdgcn_cvt_pk_fp8_f32(bq[0], bq[1], blo, 0);
    blo = __builtin_amdgcn_cvt_pk_fp8_f32(bq[2], bq[3], blo, 1);
    bhi = __builtin_amdgcn_cvt_pk_fp8_f32(bq[4], bq[5], bhi, 0);
    bhi = __builtin_amdgcn_cvt_pk_fp8_f32(bq[6], bq[7], bhi, 1);
    int pu = U ^ (a_j & 15);         // involutive swizzle baked in
    uint4 o;
    o.x = (unsigned)wlo; o.y = (unsigned)whi;
    o.z = (unsigned)blo; o.w = (unsigned)bhi;
    *(uint4*)((char*)ws + PACK_BOFF + (size_t)r * 256 + (size_t)pu * 16) = o;
}

// ================= fused pair kernel ==========================================
// r24-verified structure; order2 {vb,a_i} shortens the per-block dependent
// chain to one 8B load -> immediate stage burst. a_i-sorted XCD chunking keeps
// shared table slices L2-resident.
__global__ __launch_bounds__(256, 5) void pair_fused(const int* __restrict__ atoms,
                                                     const int* __restrict__ chirals,
                                                     const float* __restrict__ coords,
                                                     const int* __restrict__ bonds,
                                                     const float* __restrict__ atype,
                                                     const float* __restrict__ chiral,
                                                     const float* __restrict__ bond_emb,
                                                     const float* __restrict__ lin_b,
                                                     const float* __restrict__ ws,
                                                     float* __restrict__ out) {
    __shared__ __align__(16) char stage[32 * 1024];

    int t = threadIdx.x;
    int p = blockIdx.x;
    const int2* order2 = (const int2*)((const char*)ws + ORD_BOFF);
    int2 ent = order2[(p & 7) * 256 + (p >> 3)];   // a_i-sorted, XCD-chunked
    int vb = ent.x, a_i = ent.y;
    int bi = vb >> 8, i = vb & 255;
    int w = t >> 6, l = t & 63;

    // ---- one-shot stage ASAP: 8 instrs/wave, verbatim-linear (swizzle baked)
    const char* pkbi = (const char*)ws + PACK_BOFF + (size_t)a_i * 32768;
    #pragma unroll
    for (int it = 0; it < 8; ++it) {
        size_t off = (size_t)(w * 32 + it * 4) * 256 + (size_t)l * 16;
        g2lds16(pkbi + off, stage + off);
    }

    int av = atoms[bi * L + t];      // own j's atom

    float cix = coords[((size_t)bi * L + i) * 3 + 0];
    float ciy = coords[((size_t)bi * L + i) * 3 + 1];
    float ciz = coords[((size_t)bi * L + i) * 3 + 2];
    float cjx = coords[((size_t)bi * L + t) * 3 + 0];
    float cjy = coords[((size_t)bi * L + t) * 3 + 1];
    float cjz = coords[((size_t)bi * L + t) * 3 + 2];
    float dx = cjx - cix, dy = cjy - ciy, dz = cjz - ciz;
    float s2 = dx * dx + dy * dy + dz * dz;
    float d = (s2 > 0.0f) ? sqrtf(s2) : 0.0f;
    int dbits = __float_as_int(d);

    // B-frags preload (4 passes x 8 f16)
    half8v bfrag[4];
    {
        const uint4* wb = (const uint4*)((const char*)ws + WSB_BOFF);
        #pragma unroll
        for (int pp = 0; pp < 4; ++pp) {
            uint4 r = wb[pp * 64 + l];
            bfrag[pp] = *reinterpret_cast<half8v*>(&r);
        }
    }

    // compute descriptors: A-frag q covers row jq = w*64+q*16+(l&15) -> atom a;
    // pass rr, k-group m = l>>4 reads 16B unit (rr*4+m)^(a&15) of row a.
    int m = l >> 4;
    float dval[4];
    int base[4], ax[4];
    #pragma unroll
    for (int q = 0; q < 4; ++q) {
        int idx4 = (q * 16 + (l & 15)) * 4;
        int a = __builtin_amdgcn_ds_bpermute(idx4, av);
        dval[q] = __int_as_float(__builtin_amdgcn_ds_bpermute(idx4, dbits));
        base[q] = a * 256;
        ax[q] = a & 15;
    }

    float4v acc[4];
    #pragma unroll
    for (int q = 0; q < 4; ++q) { float4v z = {0, 0, 0, 0}; acc[q] = z; }

    asm volatile("s_waitcnt vmcnt(0)" ::: "memory");
    __syncthreads();                 // entire universe resident

    // ---- fused emb (overlaps compute passes; threads 0..127)
    if (t < 128) {
        int a = atoms[bi * L + i];
        int c = chirals[bi * L + i];
        const float4* va = (const float4*)(atype + (size_t)a * DM);
        const float4* vc = (const float4*)(chiral + (size_t)c * DM);
        float4 x = va[t], y = vc[t];
        x.x += y.x; x.y += y.y; x.z += y.z; x.w += y.w;
        ((float4*)(out + ((size_t)i * B + bi) * DM))[t] = x;
    }

    // ---- 4 pure-LDS K=32 passes, no global waits
    #pragma unroll
    for (int rr = 0; rr < 4; ++rr) {
        #pragma unroll
        for (int q = 0; q < 4; ++q) {
            int un = (rr * 4 + m) ^ ax[q];
            uint4 u = *(const uint4*)(stage + base[q] + (un << 4));
            auto w01 = __builtin_amdgcn_cvt_pk_f32_fp8((int)u.x, 0);
            auto w23 = __builtin_amdgcn_cvt_pk_f32_fp8((int)u.x, 1);
            auto w45 = __builtin_amdgcn_cvt_pk_f32_fp8((int)u.y, 0);
            auto w67 = __builtin_amdgcn_cvt_pk_f32_fp8((int)u.y, 1);
            auto b01 = __builtin_amdgcn_cvt_pk_f32_fp8((int)u.z, 0);
            auto b23 = __builtin_amdgcn_cvt_pk_f32_fp8((int)u.z, 1);
            auto b45 = __builtin_amdgcn_cvt_pk_f32_fp8((int)u.w, 0);
            auto b67 = __builtin_amdgcn_cvt_pk_f32_fp8((int)u.w, 1);
            float dq = dval[q];
            float t0 = fmaf(w01[0], dq, b01[0]);
            float t1 = fmaf(w01[1], dq, b01[1]);
            float t2 = fmaf(w23[0], dq, b23[0]);
            float t3 = fmaf(w23[1], dq, b23[1]);
            float t4 = fmaf(w45[0], dq, b45[0]);
            float t5 = fmaf(w45[1], dq, b45[1]);
            float t6 = fmaf(w67[0], dq, b67[0]);
            float t7 = fmaf(w67[1], dq, b67[1]);
            float g0 = __builtin_amdgcn_exp2f(-(t0 * t0));
            float g1 = __builtin_amdgcn_exp2f(-(t1 * t1));
            float g2 = __builtin_amdgcn_exp2f(-(t2 * t2));
            float g3 = __builtin_amdgcn_exp2f(-(t3 * t3));
            float g4 = __builtin_amdgcn_exp2f(-(t4 * t4));
            float g5 = __builtin_amdgcn_exp2f(-(t5 * t5));
            float g6 = __builtin_amdgcn_exp2f(-(t6 * t6));
            float g7 = __builtin_amdgcn_exp2f(-(t7 * t7));
            auto p0 = __builtin_amdgcn_cvt_pkrtz(g0, g1);
            auto p1 = __builtin_amdgcn_cvt_pkrtz(g2, g3);
            auto p2 = __builtin_amdgcn_cvt_pkrtz(g4, g5);
            auto p3 = __builtin_amdgcn_cvt_pkrtz(g6, g7);
            uint4 au;
            au.x = *reinterpret_cast<unsigned*>(&p0);
            au.y = *reinterpret_cast<unsigned*>(&p1);
            au.z = *reinterpret_cast<unsigned*>(&p2);
            au.w = *reinterpret_cast<unsigned*>(&p3);
            half8v af = *reinterpret_cast<half8v*>(&au);
            acc[q] = __builtin_amdgcn_mfma_f32_16x16x32_f16(af, bfrag[rr],
                                                            acc[q], 0, 0, 0);
        }
    }

    asm volatile("s_waitcnt lgkmcnt(0)" ::: "memory");
    __syncthreads();                 // all reads done -> reuse stage as cbuf

    // ---- epilogue: transpose C (col h=l&15, row j=16q+(l>>4)*4+reg)
    int a_j = atoms[bi * L + t];
    int bvd = bonds[(((size_t)bi * L) + i) * L + t];
    float beh[NH];
    {
        const float4* ber = (const float4*)(bond_emb + (size_t)bvd * NH);
        #pragma unroll
        for (int u = 0; u < 4; ++u) {
            float4 v4 = ber[u];
            beh[u * 4 + 0] = v4.x; beh[u * 4 + 1] = v4.y;
            beh[u * 4 + 2] = v4.z; beh[u * 4 + 3] = v4.w;
        }
    }
    float* cbuf = (float*)(stage + (size_t)w * 4352);   // 16 x 68 floats/wave
    {
        int h = l & 15, jg = l >> 4;
        #pragma unroll
        for (int q = 0; q < 4; ++q)
            *(float4v*)(cbuf + h * 68 + q * 16 + jg * 4) = acc[q];
    }
    asm volatile("s_waitcnt lgkmcnt(0)" ::: "memory");
    __builtin_amdgcn_sched_barrier(0);

    size_t obase = (((size_t)bi * NH) * L + i) * L + t;
    // PAD column -> most-negative FINITE bf16 (0xff7f0000); survives harness bf16 cast.
    float ninf = __uint_as_float(0xff7f0000u);
    bool pad = (a_j == 0);
    #pragma unroll
    for (int h = 0; h < NH; ++h) {
        float v = cbuf[h * 68 + l] + lin_b[h] + beh[h];
        out[(size_t)EMB + obase + (size_t)h * L * L] = pad ? ninf : v;
    }
}

extern "C" void kernel_launch(void* const* d_in, const int* in_sizes, int n_in,
                              void* d_out, int out_size, void* d_ws, size_t ws_size,
                              hipStream_t stream) {
    const int*   atoms    = (const int*)d_in[0];
    const int*   chirals  = (const int*)d_in[1];
    const float* coords   = (const float*)d_in[2];
    const int*   bonds    = (const int*)d_in[3];
    const float* atype    = (const float*)d_in[4];
    const float* chiral   = (const float*)d_in[5];
    const float* wtab     = (const float*)d_in[6];
    const float* btab     = (const float*)d_in[7];
    const float* means    = (const float*)d_in[8];
    const float* stds     = (const float*)d_in[9];
    const float* bond_emb = (const float*)d_in[10];
    const float* lin_w    = (const float*)d_in[11];
    const float* lin_b    = (const float*)d_in[12];
    float* out = (float*)d_out;
    float* ws  = (float*)d_ws;

    pack_kernel<<<1024, 256, 0, stream>>>(wtab, btab, means, stds, lin_w, atoms, ws);
    pair_fused<<<B * L, 256, 0, stream>>>(atoms, chirals, coords, bonds,
                                          atype, chiral, bond_emb, lin_b, ws, out);
}